// Round 8
// baseline (575.329 us; speedup 1.0000x reference)
//
#include <hip/hip_runtime.h>
#include <math.h>

#define MTOT 32768   // B*S tokens
#define MT   64      // tokens per block
#define NBLK (MTOT / MT)

typedef __attribute__((ext_vector_type(8))) short short8;   // 8 x bf16
typedef __attribute__((ext_vector_type(4))) float f32x4;
typedef __attribute__((ext_vector_type(4))) unsigned int uint4v;

__device__ __forceinline__ unsigned short f2b(float f) {
  unsigned int u = __builtin_bit_cast(unsigned int, f);
  u = (u + 0x7fffu + ((u >> 16) & 1u)) >> 16;   // RNE fp32->bf16
  return (unsigned short)u;
}
__device__ __forceinline__ float b2f(unsigned short h) {
  unsigned int u = ((unsigned int)h) << 16;
  return __builtin_bit_cast(float, u);
}
__device__ __forceinline__ float fast_tanh(float x) {
  float e = __expf(2.0f * x);
  return 1.0f - 2.0f / (e + 1.0f);
}

// ---------------------------------------------------------------------------
// Transpose all four [512][512] fp32 weights into [N][K] bf16 in one launch.
// ---------------------------------------------------------------------------
__global__ __launch_bounds__(256)
void transpose_w4(const float* __restrict__ i0, const float* __restrict__ i1,
                  const float* __restrict__ i2, const float* __restrict__ i3,
                  unsigned short* __restrict__ o0, unsigned short* __restrict__ o1,
                  unsigned short* __restrict__ o2, unsigned short* __restrict__ o3) {
  const float* in;
  unsigned short* out;
  switch (blockIdx.z) {
    case 0: in = i0; out = o0; break;
    case 1: in = i1; out = o1; break;
    case 2: in = i2; out = o2; break;
    default: in = i3; out = o3; break;
  }
  __shared__ float t[32][33];
  const int tx = threadIdx.x, ty = threadIdx.y;       // 32 x 8
  const int n0 = blockIdx.x * 32, k0 = blockIdx.y * 32;
  #pragma unroll
  for (int i = 0; i < 32; i += 8)
    t[ty + i][tx] = in[(size_t)(k0 + ty + i) * 512 + (n0 + tx)];
  __syncthreads();
  #pragma unroll
  for (int i = 0; i < 32; i += 8)
    out[(size_t)(n0 + ty + i) * 512 + (k0 + tx)] = f2b(t[tx][ty + i]);
}

// ---------------------------------------------------------------------------
// Megakernel: per block, MT=64 tokens flow through the ENTIRE pipeline with
// activations resident in a 64KB LDS tile act[64][512] (bf16).
//   stage0 tanh / stage1 none / kuramoto / stage2 relu / stage3 out4+noise
// LDS swizzle: 16B chunk c of row r stored at phys chunk c ^ (r&7).
// B (weights, 2MB -> L2-resident) read DIRECTLY global->VGPR, software-
// pipelined ONE kc AHEAD (ping/pong bf sets, full kc unroll -> static
// indices).  R7 profile: MfmaUtil 9.9%, VALU 25%, HBM 17%, occ 21% ->
// latency-bound; loads were issued in the same kc that consumed them,
// exposing ~250cyc L2 latency per kc.  Prefetch hides it under the 32-MFMA
// block (~160cyc) x 2 waves/SIMD.
// History: (256,4) reg-cap -> acc scratch spill (R6, hbm +120MB, slower).
// ---------------------------------------------------------------------------
template<int SACT>   // 0=tanh, 1=none, 2=relu, 3=final(out4+noise)
__device__ __forceinline__ void do_stage(
    unsigned short* act,
    const unsigned short* __restrict__ wt,
    const float* __restrict__ bias,
    const int wave, const int lane, const int r0,
    const float* __restrict__ noise,
    const float* __restrict__ alphap,
    float* __restrict__ out4)
{
  const int quad = lane >> 4, l16 = lane & 15;
  const int bn = wave * 128;

  const unsigned short* wp[8];
  #pragma unroll
  for (int ni = 0; ni < 8; ++ni)
    wp[ni] = wt + (size_t)(bn + ni * 16 + l16) * 512 + quad * 8;

  f32x4 acc[4][8] = {};

  // ---- K-loop, software-pipelined: bf ping/pong, prefetch kc+1.
  // Full unroll => bf[kc&1] indices are compile-time (no scratch, rule #20).
  short8 bf[2][8];
  #pragma unroll
  for (int ni = 0; ni < 8; ++ni) bf[0][ni] = *(const short8*)(wp[ni]);

  #pragma unroll 16
  for (int kc = 0; kc < 16; ++kc) {
    const int cur = kc & 1, nxt = cur ^ 1;
    if (kc < 15) {
      #pragma unroll
      for (int ni = 0; ni < 8; ++ni)
        bf[nxt][ni] = *(const short8*)(wp[ni] + (kc + 1) * 32);
    }
    // A fragments from LDS; (mi*16+l16)&7 == l16&7 -> same phys chunk all mi
    const int p = ((4 * kc + quad) ^ (l16 & 7)) * 8;
    short8 af[4];
    #pragma unroll
    for (int mi = 0; mi < 4; ++mi)
      af[mi] = *(const short8*)&act[(mi * 16 + l16) * 512 + p];
    __builtin_amdgcn_s_setprio(1);
    #pragma unroll
    for (int ni = 0; ni < 8; ++ni)
      #pragma unroll
      for (int mi = 0; mi < 4; ++mi)
        acc[mi][ni] = __builtin_amdgcn_mfma_f32_16x16x32_bf16(
            af[mi], bf[cur][ni], acc[mi][ni], 0, 0, 0);
    __builtin_amdgcn_s_setprio(0);
  }

  float bv[8];
  #pragma unroll
  for (int ni = 0; ni < 8; ++ni) bv[ni] = bias[bn + ni * 16 + l16];

  if (SACT == 3) {
    // final epilogue: out[m][n][4] fp32 = {c, im, im, im}
    const float alpha = alphap[0];
    float fmod[8];
    #pragma unroll
    for (int ni = 0; ni < 8; ++ni)
      fmod[ni] = sinf(alpha * (float)(bn + ni * 16 + l16));
    #pragma unroll
    for (int mi = 0; mi < 4; ++mi) {
      #pragma unroll
      for (int ni = 0; ni < 8; ++ni) {
        const int n = bn + ni * 16 + l16;
        #pragma unroll
        for (int r = 0; r < 4; ++r) {
          const int m = r0 + mi * 16 + quad * 4 + r;
          const float c  = acc[mi][ni][r] + bv[ni];
          const float im = noise[(size_t)m * 512 + n] * fmod[ni];
          f32x4 o; o[0] = c; o[1] = im; o[2] = im; o[3] = im;
          *(f32x4*)&out4[((size_t)m * 512 + n) * 4] = o;   // 16B coalesced
        }
      }
    }
  } else {
    __syncthreads();   // all K-loop reads of act complete before overwrite
    #pragma unroll
    for (int mi = 0; mi < 4; ++mi) {
      #pragma unroll
      for (int ni = 0; ni < 8; ++ni) {
        const int col = bn + ni * 16 + l16;
        #pragma unroll
        for (int r = 0; r < 4; ++r) {
          const int row = mi * 16 + quad * 4 + r;
          float c = acc[mi][ni][r] + bv[ni];
          if (SACT == 0) c = fast_tanh(c);
          if (SACT == 2) c = fmaxf(c, 0.0f);
          const int phys = (col >> 3) ^ (row & 7);
          act[row * 512 + phys * 8 + (col & 7)] = f2b(c);
        }
      }
    }
    __syncthreads();   // writes visible before next stage's reads
  }
}

__global__ __launch_bounds__(256, 2)
void mega_k(const float* __restrict__ x,
            const unsigned short* __restrict__ wt1, const float* __restrict__ b1,
            const unsigned short* __restrict__ wt2, const float* __restrict__ b2,
            const unsigned short* __restrict__ wt3, const float* __restrict__ c1,
            const unsigned short* __restrict__ wt4, const float* __restrict__ c2,
            const float* __restrict__ omega, const float* __restrict__ Kp,
            const float* __restrict__ alphap, const float* __restrict__ noise,
            float* __restrict__ out)
{
  __shared__ __align__(16) unsigned short act[MT * 512];   // 64 KB

  const int tid  = threadIdx.x;
  const int wave = tid >> 6, lane = tid & 63;
  const int r0   = blockIdx.x * MT;

  // ---- x [MT][512] fp32 -> bf16 into swizzled act.
  #pragma unroll
  for (int j = 0; j < 16; ++j) {
    const int r  = wave * 16 + j;
    const int lc = lane ^ (r & 7);
    const float* src = x + (size_t)(r0 + r) * 512 + lc * 8;
    f32x4 a = *(const f32x4*)src;
    f32x4 b = *(const f32x4*)(src + 4);
    unsigned short t[8] __attribute__((aligned(16)));
    t[0] = f2b(a[0]); t[1] = f2b(a[1]); t[2] = f2b(a[2]); t[3] = f2b(a[3]);
    t[4] = f2b(b[0]); t[5] = f2b(b[1]); t[6] = f2b(b[2]); t[7] = f2b(b[3]);
    *(uint4v*)&act[r * 512 + lane * 8] = *(const uint4v*)t;
  }
  __syncthreads();

  do_stage<0>(act, wt1, b1, wave, lane, r0, nullptr, nullptr, nullptr);
  do_stage<1>(act, wt2, b2, wave, lane, r0, nullptr, nullptr, nullptr);

  // ---- Kuramoto: wave handles rows wave*16 .. wave*16+15 sequentially.
  {
    const float Ks = Kp[0] * (1.0f / 512.0f);
    float om[8];
    #pragma unroll
    for (int i = 0; i < 8; ++i) om[i] = omega[i * 64 + lane];
    for (int j = 0; j < 16; ++j) {
      const int r = wave * 16 + j;
      float ph[8];
      #pragma unroll
      for (int i = 0; i < 8; ++i) {
        const int col = i * 64 + lane;
        const int phys = (col >> 3) ^ (r & 7);
        ph[i] = b2f(act[r * 512 + phys * 8 + (col & 7)]);
      }
      #pragma unroll
      for (int s = 0; s < 10; ++s) {
        float sum = 0.0f;
        #pragma unroll
        for (int i = 0; i < 8; ++i) sum += __sinf(ph[i]);
        #pragma unroll
        for (int off = 32; off > 0; off >>= 1) sum += __shfl_xor(sum, off, 64);
        const float mf = Ks * sum;
        #pragma unroll
        for (int i = 0; i < 8; ++i) ph[i] += 0.01f * (om[i] + mf * __cosf(ph[i]));
      }
      #pragma unroll
      for (int i = 0; i < 8; ++i) {
        const int col = i * 64 + lane;
        const int phys = (col >> 3) ^ (r & 7);
        act[r * 512 + phys * 8 + (col & 7)] = f2b(ph[i]);
      }
    }
  }
  __syncthreads();

  do_stage<2>(act, wt3, c1, wave, lane, r0, nullptr, nullptr, nullptr);
  do_stage<3>(act, wt4, c2, wave, lane, r0, noise, alphap, out);
}

// ---------------------------------------------------------------------------
extern "C" void kernel_launch(void* const* d_in, const int* in_sizes, int n_in,
                              void* d_out, int out_size, void* d_ws, size_t ws_size,
                              hipStream_t stream) {
  const float* x      = (const float*)d_in[0];
  const float* W1     = (const float*)d_in[1];
  const float* b1     = (const float*)d_in[2];
  const float* W2     = (const float*)d_in[3];
  const float* b2     = (const float*)d_in[4];
  const float* omega  = (const float*)d_in[5];
  const float* Kp     = (const float*)d_in[6];
  const float* alphap = (const float*)d_in[7];
  const float* F1     = (const float*)d_in[8];
  const float* c1     = (const float*)d_in[9];
  const float* F2     = (const float*)d_in[10];
  const float* c2     = (const float*)d_in[11];
  const float* noise  = (const float*)d_in[12];
  float* out = (float*)d_out;

  // workspace: 4 x 512KB bf16 transposed weights
  char* ws = (char*)d_ws;
  unsigned short* wt1 = (unsigned short*)(ws + 0 * (512 * 1024));
  unsigned short* wt2 = (unsigned short*)(ws + 1 * (512 * 1024));
  unsigned short* wt3 = (unsigned short*)(ws + 2 * (512 * 1024));
  unsigned short* wt4 = (unsigned short*)(ws + 3 * (512 * 1024));

  dim3 tb(32, 8), tg(16, 16, 4);
  transpose_w4<<<tg, tb, 0, stream>>>(W1, W2, F1, F2, wt1, wt2, wt3, wt4);
  mega_k<<<NBLK, 256, 0, stream>>>(x, wt1, b1, wt2, b2, wt3, c1, wt4, c2,
                                   omega, Kp, alphap, noise, out);
}

// Round 9
// 547.399 us; speedup vs baseline: 1.0510x; 1.0510x over previous
//
#include <hip/hip_runtime.h>
#include <math.h>

#define MTOT 32768   // B*S tokens
#define MT   64      // tokens per block
#define NBLK (MTOT / MT)

typedef __attribute__((ext_vector_type(8))) short short8;   // 8 x bf16
typedef __attribute__((ext_vector_type(4))) float f32x4;
typedef __attribute__((ext_vector_type(4))) unsigned int uint4v;

__device__ __forceinline__ unsigned short f2b(float f) {
  unsigned int u = __builtin_bit_cast(unsigned int, f);
  u = (u + 0x7fffu + ((u >> 16) & 1u)) >> 16;   // RNE fp32->bf16
  return (unsigned short)u;
}
__device__ __forceinline__ float b2f(unsigned short h) {
  unsigned int u = ((unsigned int)h) << 16;
  return __builtin_bit_cast(float, u);
}
__device__ __forceinline__ float fast_tanh(float x) {
  float e = __expf(2.0f * x);
  return 1.0f - 2.0f / (e + 1.0f);
}

// ---------------------------------------------------------------------------
// Transpose all four [512][512] fp32 weights into [N][K] bf16 in one launch.
// ---------------------------------------------------------------------------
__global__ __launch_bounds__(256)
void transpose_w4(const float* __restrict__ i0, const float* __restrict__ i1,
                  const float* __restrict__ i2, const float* __restrict__ i3,
                  unsigned short* __restrict__ o0, unsigned short* __restrict__ o1,
                  unsigned short* __restrict__ o2, unsigned short* __restrict__ o3) {
  const float* in;
  unsigned short* out;
  switch (blockIdx.z) {
    case 0: in = i0; out = o0; break;
    case 1: in = i1; out = o1; break;
    case 2: in = i2; out = o2; break;
    default: in = i3; out = o3; break;
  }
  __shared__ float t[32][33];
  const int tx = threadIdx.x, ty = threadIdx.y;       // 32 x 8
  const int n0 = blockIdx.x * 32, k0 = blockIdx.y * 32;
  #pragma unroll
  for (int i = 0; i < 32; i += 8)
    t[ty + i][tx] = in[(size_t)(k0 + ty + i) * 512 + (n0 + tx)];
  __syncthreads();
  #pragma unroll
  for (int i = 0; i < 32; i += 8)
    out[(size_t)(n0 + ty + i) * 512 + (k0 + tx)] = f2b(t[tx][ty + i]);
}

// ---------------------------------------------------------------------------
// Megakernel, 512 threads (8 waves): per block, MT=64 tokens flow through
// the ENTIRE pipeline with activations resident in a 64KB LDS act[64][512]
// (bf16, 16B-chunk XOR swizzle: phys chunk = c ^ (r&7)).
//   stage0 tanh / stage1 none / kuramoto / stage2 relu / stage3 out4+noise
// Each wave owns a 64-col N-slice (4 ni): acc 4x4 f32x4 = 64 regs.  This
// fits the 128-reg cap of 4 waves/EU -> 2 blocks/CU co-resident (LDS
// 2x64KB) = 4 waves/SIMD of TLP to hide the ~250cyc L2 B-load latency.
// History: R7 (4-wave, 128-col slices, acc=128) = register ceiling at
// (256,2) -> only 2 waves/SIMD, MfmaUtil 9.9%, latency-bound 285us.
// R8 in-register B-prefetch -> spill (sym +41MB FETCH/WRITE), 303us.
// R6 (256,4) with acc=128 -> forced spill, 380us.  TLP must come from
// SMALLER per-wave state, not caps or ILP.
// ---------------------------------------------------------------------------
template<int SACT>   // 0=tanh, 1=none, 2=relu, 3=final(out4+noise)
__device__ __forceinline__ void do_stage(
    unsigned short* act,
    const unsigned short* __restrict__ wt,
    const float* __restrict__ bias,
    const int wave, const int lane, const int r0,
    const float* __restrict__ noise,
    const float* __restrict__ alphap,
    float* __restrict__ out4)
{
  const int quad = lane >> 4, l16 = lane & 15;
  const int bn = wave * 64;          // this wave's N-slice

  const unsigned short* wp[4];
  #pragma unroll
  for (int ni = 0; ni < 4; ++ni)
    wp[ni] = wt + (size_t)(bn + ni * 16 + l16) * 512 + quad * 8;

  f32x4 acc[4][4] = {};

  #pragma unroll 2
  for (int kc = 0; kc < 16; ++kc) {
    // A fragments from LDS; (mi*16+l16)&7 == l16&7 -> same phys chunk all mi
    const int p = ((4 * kc + quad) ^ (l16 & 7)) * 8;
    short8 af[4];
    #pragma unroll
    for (int mi = 0; mi < 4; ++mi)
      af[mi] = *(const short8*)&act[(mi * 16 + l16) * 512 + p];
    // B fragments direct from global (L2): 16B/lane, imm-offset folded
    short8 bf[4];
    #pragma unroll
    for (int ni = 0; ni < 4; ++ni)
      bf[ni] = *(const short8*)(wp[ni] + kc * 32);
    __builtin_amdgcn_s_setprio(1);
    #pragma unroll
    for (int ni = 0; ni < 4; ++ni)
      #pragma unroll
      for (int mi = 0; mi < 4; ++mi)
        acc[mi][ni] = __builtin_amdgcn_mfma_f32_16x16x32_bf16(
            af[mi], bf[ni], acc[mi][ni], 0, 0, 0);
    __builtin_amdgcn_s_setprio(0);
  }

  float bv[4];
  #pragma unroll
  for (int ni = 0; ni < 4; ++ni) bv[ni] = bias[bn + ni * 16 + l16];

  if (SACT == 3) {
    // final epilogue: out[m][n][4] fp32 = {c, im, im, im}
    const float alpha = alphap[0];
    float fmod[4];
    #pragma unroll
    for (int ni = 0; ni < 4; ++ni)
      fmod[ni] = sinf(alpha * (float)(bn + ni * 16 + l16));
    #pragma unroll
    for (int mi = 0; mi < 4; ++mi) {
      #pragma unroll
      for (int ni = 0; ni < 4; ++ni) {
        const int n = bn + ni * 16 + l16;
        #pragma unroll
        for (int r = 0; r < 4; ++r) {
          const int m = r0 + mi * 16 + quad * 4 + r;
          const float c  = acc[mi][ni][r] + bv[ni];
          const float im = noise[(size_t)m * 512 + n] * fmod[ni];
          f32x4 o; o[0] = c; o[1] = im; o[2] = im; o[3] = im;
          *(f32x4*)&out4[((size_t)m * 512 + n) * 4] = o;   // 16B coalesced
        }
      }
    }
  } else {
    __syncthreads();   // all K-loop reads of act complete before overwrite
    #pragma unroll
    for (int mi = 0; mi < 4; ++mi) {
      #pragma unroll
      for (int ni = 0; ni < 4; ++ni) {
        const int col = bn + ni * 16 + l16;
        #pragma unroll
        for (int r = 0; r < 4; ++r) {
          const int row = mi * 16 + quad * 4 + r;
          float c = acc[mi][ni][r] + bv[ni];
          if (SACT == 0) c = fast_tanh(c);
          if (SACT == 2) c = fmaxf(c, 0.0f);
          const int phys = (col >> 3) ^ (row & 7);
          act[row * 512 + phys * 8 + (col & 7)] = f2b(c);
        }
      }
    }
    __syncthreads();   // writes visible before next stage's reads
  }
}

__global__ __launch_bounds__(512, 4)
void mega_k(const float* __restrict__ x,
            const unsigned short* __restrict__ wt1, const float* __restrict__ b1,
            const unsigned short* __restrict__ wt2, const float* __restrict__ b2,
            const unsigned short* __restrict__ wt3, const float* __restrict__ c1,
            const unsigned short* __restrict__ wt4, const float* __restrict__ c2,
            const float* __restrict__ omega, const float* __restrict__ Kp,
            const float* __restrict__ alphap, const float* __restrict__ noise,
            float* __restrict__ out)
{
  __shared__ __align__(16) unsigned short act[MT * 512];   // 64 KB

  const int tid  = threadIdx.x;
  const int wave = tid >> 6, lane = tid & 63;
  const int r0   = blockIdx.x * MT;

  // ---- x [MT][512] fp32 -> bf16 into swizzled act.  8 waves x 8 rows.
  #pragma unroll
  for (int j = 0; j < 8; ++j) {
    const int r  = wave * 8 + j;
    const int lc = lane ^ (r & 7);
    const float* src = x + (size_t)(r0 + r) * 512 + lc * 8;
    f32x4 a = *(const f32x4*)src;
    f32x4 b = *(const f32x4*)(src + 4);
    unsigned short t[8] __attribute__((aligned(16)));
    t[0] = f2b(a[0]); t[1] = f2b(a[1]); t[2] = f2b(a[2]); t[3] = f2b(a[3]);
    t[4] = f2b(b[0]); t[5] = f2b(b[1]); t[6] = f2b(b[2]); t[7] = f2b(b[3]);
    *(uint4v*)&act[r * 512 + lane * 8] = *(const uint4v*)t;
  }
  __syncthreads();

  do_stage<0>(act, wt1, b1, wave, lane, r0, nullptr, nullptr, nullptr);
  do_stage<1>(act, wt2, b2, wave, lane, r0, nullptr, nullptr, nullptr);

  // ---- Kuramoto: wave handles rows wave*8 .. wave*8+7 sequentially.
  {
    const float Ks = Kp[0] * (1.0f / 512.0f);
    float om[8];
    #pragma unroll
    for (int i = 0; i < 8; ++i) om[i] = omega[i * 64 + lane];
    for (int j = 0; j < 8; ++j) {
      const int r = wave * 8 + j;
      float ph[8];
      #pragma unroll
      for (int i = 0; i < 8; ++i) {
        const int col = i * 64 + lane;
        const int phys = (col >> 3) ^ (r & 7);
        ph[i] = b2f(act[r * 512 + phys * 8 + (col & 7)]);
      }
      #pragma unroll
      for (int s = 0; s < 10; ++s) {
        float sum = 0.0f;
        #pragma unroll
        for (int i = 0; i < 8; ++i) sum += __sinf(ph[i]);
        #pragma unroll
        for (int off = 32; off > 0; off >>= 1) sum += __shfl_xor(sum, off, 64);
        const float mf = Ks * sum;
        #pragma unroll
        for (int i = 0; i < 8; ++i) ph[i] += 0.01f * (om[i] + mf * __cosf(ph[i]));
      }
      #pragma unroll
      for (int i = 0; i < 8; ++i) {
        const int col = i * 64 + lane;
        const int phys = (col >> 3) ^ (r & 7);
        act[r * 512 + phys * 8 + (col & 7)] = f2b(ph[i]);
      }
    }
  }
  __syncthreads();

  do_stage<2>(act, wt3, c1, wave, lane, r0, nullptr, nullptr, nullptr);
  do_stage<3>(act, wt4, c2, wave, lane, r0, noise, alphap, out);
}

// ---------------------------------------------------------------------------
extern "C" void kernel_launch(void* const* d_in, const int* in_sizes, int n_in,
                              void* d_out, int out_size, void* d_ws, size_t ws_size,
                              hipStream_t stream) {
  const float* x      = (const float*)d_in[0];
  const float* W1     = (const float*)d_in[1];
  const float* b1     = (const float*)d_in[2];
  const float* W2     = (const float*)d_in[3];
  const float* b2     = (const float*)d_in[4];
  const float* omega  = (const float*)d_in[5];
  const float* Kp     = (const float*)d_in[6];
  const float* alphap = (const float*)d_in[7];
  const float* F1     = (const float*)d_in[8];
  const float* c1     = (const float*)d_in[9];
  const float* F2     = (const float*)d_in[10];
  const float* c2     = (const float*)d_in[11];
  const float* noise  = (const float*)d_in[12];
  float* out = (float*)d_out;

  // workspace: 4 x 512KB bf16 transposed weights
  char* ws = (char*)d_ws;
  unsigned short* wt1 = (unsigned short*)(ws + 0 * (512 * 1024));
  unsigned short* wt2 = (unsigned short*)(ws + 1 * (512 * 1024));
  unsigned short* wt3 = (unsigned short*)(ws + 2 * (512 * 1024));
  unsigned short* wt4 = (unsigned short*)(ws + 3 * (512 * 1024));

  dim3 tb(32, 8), tg(16, 16, 4);
  transpose_w4<<<tg, tb, 0, stream>>>(W1, W2, F1, F2, wt1, wt2, wt3, wt4);
  mega_k<<<NBLK, 512, 0, stream>>>(x, wt1, b1, wt2, b2, wt3, c1, wt4, c2,
                                   omega, Kp, alphap, noise, out);
}